// Round 1
// baseline (5327.954 us; speedup 1.0000x reference)
//
#include <hip/hip_runtime.h>
#include <math.h>

#define NN 100000
#define NE 1600000
#define NG 2048

// ---------------- degree / norm ----------------
__global__ __launch_bounds__(256) void deg_kernel(const int* __restrict__ dst,
                                                  float* __restrict__ deg, int E) {
    int e = blockIdx.x * 256 + threadIdx.x;
    if (e < E) atomicAdd(&deg[dst[e]], 1.0f);
}

__global__ __launch_bounds__(256) void dinv_kernel(float* __restrict__ deg, int N) {
    int i = blockIdx.x * 256 + threadIdx.x;
    if (i < N) deg[i] = rsqrtf(deg[i] + 1.0f);   // in-place: deg -> dinv
}

__global__ __launch_bounds__(256) void coef_kernel(const int* __restrict__ src,
                                                   const int* __restrict__ dst,
                                                   const float* __restrict__ dinv,
                                                   float* __restrict__ coef, int E) {
    int e = blockIdx.x * 256 + threadIdx.x;
    if (e < E) coef[e] = dinv[src[e]] * dinv[dst[e]];
}

// ---------------- dense: out[N,FOUT] = (relu?)in[N,FIN] @ W[FIN,FOUT] ----------------
template<int FIN, int FOUT, bool RELU_IN>
__global__ __launch_bounds__(256) void gemm_kernel(const float* __restrict__ in,
                                                   const float* __restrict__ W,
                                                   float* __restrict__ out, int N) {
    constexpr int NPB = 256 / FOUT;      // rows in flight
    constexpr int ROWS = 64;             // rows per block
    __shared__ float Wl[FIN * FOUT];
    __shared__ float xr[NPB][FIN];
    const int t = threadIdx.x;
    for (int i = t; i < FIN * FOUT; i += 256) Wl[i] = W[i];
    const int f  = t % FOUT;
    const int ns = t / FOUT;
    const int base = blockIdx.x * ROWS;
    for (int n0 = 0; n0 < ROWS; n0 += NPB) {
        __syncthreads();                 // first pass also covers Wl
        for (int i = t; i < NPB * FIN; i += 256) {
            int nn = base + n0 + i / FIN;
            float v = (nn < N) ? in[(size_t)nn * FIN + (i % FIN)] : 0.0f;
            if (RELU_IN) v = fmaxf(v, 0.0f);
            xr[i / FIN][i % FIN] = v;
        }
        __syncthreads();
        float acc = 0.0f;
#pragma unroll
        for (int k = 0; k < FIN; ++k)
            acc = fmaf(xr[ns][k], Wl[k * FOUT + f], acc);
        int n = base + n0 + ns;
        if (n < N) out[(size_t)n * FOUT + f] = acc;
    }
}

// ---------------- agg init: agg = h*dinv^2 + b (self-loop + bias) ----------------
template<int F>
__global__ __launch_bounds__(256) void agginit_kernel(const float* __restrict__ h,
                                                      const float* __restrict__ dinv,
                                                      const float* __restrict__ b,
                                                      float* __restrict__ agg, int N) {
    constexpr int TPN = F / 4;
    int tid = blockIdx.x * 256 + threadIdx.x;
    int n = tid / TPN, r = tid % TPN;
    if (n >= N) return;
    float di = dinv[n];
    float c = di * di;
    const float4 hv = *(const float4*)(h + (size_t)n * F + r * 4);
    const float4 bv = *(const float4*)(b + r * 4);
    float4 o;
    o.x = fmaf(hv.x, c, bv.x);
    o.y = fmaf(hv.y, c, bv.y);
    o.z = fmaf(hv.z, c, bv.z);
    o.w = fmaf(hv.w, c, bv.w);
    *(float4*)(agg + (size_t)n * F + r * 4) = o;
}

// ---------------- edge scatter: agg[dst] += coef * h[src] ----------------
template<int F>
__global__ __launch_bounds__(256) void scatter_kernel(const int* __restrict__ src,
                                                      const int* __restrict__ dst,
                                                      const float* __restrict__ coef,
                                                      const float* __restrict__ h,
                                                      float* __restrict__ agg, int E) {
    constexpr int TPE = F / 4;
    int tid = blockIdx.x * 256 + threadIdx.x;
    int e = tid / TPE, r = tid % TPE;
    if (e >= E) return;
    int s = src[e], d = dst[e];
    float c = coef[e];
    const float4 hv = *(const float4*)(h + (size_t)s * F + r * 4);
    float* o = agg + (size_t)d * F + r * 4;
    atomicAdd(o + 0, hv.x * c);
    atomicAdd(o + 1, hv.y * c);
    atomicAdd(o + 2, hv.z * c);
    atomicAdd(o + 3, hv.w * c);
}

// ---------------- pooling ----------------
__global__ __launch_bounds__(256) void cnt_kernel(const int* __restrict__ batch,
                                                  float* __restrict__ cnt, int N) {
    int i = blockIdx.x * 256 + threadIdx.x;
    if (i < N) atomicAdd(&cnt[batch[i]], 1.0f);
}

__global__ __launch_bounds__(256) void pool_kernel(const float* __restrict__ h,
                                                   const int* __restrict__ batch,
                                                   float* __restrict__ sums, int N) {
    int tid = blockIdx.x * 256 + threadIdx.x;
    int n = tid / 8, r = tid % 8;
    if (n >= N) return;
    int g = batch[n];
    const float4 hv = *(const float4*)(h + (size_t)n * 32 + r * 4);
    float* o = sums + (size_t)g * 32 + r * 4;
    atomicAdd(o + 0, hv.x);
    atomicAdd(o + 1, hv.y);
    atomicAdd(o + 2, hv.z);
    atomicAdd(o + 3, hv.w);
}

// ---------------- epilogue: logits, sigmoid, BCE mean (one block) ----------------
__global__ __launch_bounds__(256) void final_kernel(const float* __restrict__ sums,
                                                    const float* __restrict__ cnt,
                                                    const float* __restrict__ Wl,
                                                    const float* __restrict__ bl,
                                                    const int* __restrict__ targets,
                                                    float* __restrict__ out) {
    __shared__ float red[256];
    float lsum = 0.0f;
    for (int g = threadIdx.x; g < NG; g += 256) {
        float c = fmaxf(cnt[g], 1.0f);
        float acc = bl[0];
#pragma unroll
        for (int k = 0; k < 32; ++k)
            acc = fmaf(sums[g * 32 + k] / c, Wl[k], acc);
        out[g] = 1.0f / (1.0f + expf(-acc));
        float y = (float)targets[g];
        lsum += fmaxf(acc, 0.0f) - acc * y + log1pf(expf(-fabsf(acc)));
    }
    red[threadIdx.x] = lsum;
    __syncthreads();
    for (int s = 128; s > 0; s >>= 1) {
        if (threadIdx.x < s) red[threadIdx.x] += red[threadIdx.x + s];
        __syncthreads();
    }
    if (threadIdx.x == 0) out[NG] = red[0] / (float)NG;
}

extern "C" void kernel_launch(void* const* d_in, const int* in_sizes, int n_in,
                              void* d_out, int out_size, void* d_ws, size_t ws_size,
                              hipStream_t stream) {
    const float* x       = (const float*)d_in[0];
    const int*   ei      = (const int*)d_in[1];
    const int*   batch   = (const int*)d_in[2];
    const int*   targets = (const int*)d_in[3];
    const float* W1 = (const float*)d_in[4];
    const float* b1 = (const float*)d_in[5];
    const float* W2 = (const float*)d_in[6];
    const float* b2 = (const float*)d_in[7];
    const float* W3 = (const float*)d_in[8];
    const float* b3 = (const float*)d_in[9];
    const float* Wl = (const float*)d_in[10];
    const float* bl = (const float*)d_in[11];
    float* out = (float*)d_out;
    float* ws  = (float*)d_ws;

    const int* src = ei;
    const int* dst = ei + NE;

    // workspace layout (floats, 512B-aligned offsets); peak ~109.5 MB
    float* dinv = ws;                    // 100000 (pad 100352)
    float* coef = ws + 100352;           // 1600000 (pad 1600512)
    float* bufA = coef + 1600512;        // 12.8M floats
    float* bufB = bufA + 12800000;       // 12.8M floats
    float* sums = bufB + 12800000;       // 65536
    float* cnt  = sums + 65536;          // 2048

    // degrees -> dinv -> per-edge coef
    hipMemsetAsync(dinv, 0, NN * sizeof(float), stream);
    deg_kernel<<<(NE + 255) / 256, 256, 0, stream>>>(dst, dinv, NE);
    dinv_kernel<<<(NN + 255) / 256, 256, 0, stream>>>(dinv, NN);
    coef_kernel<<<(NE + 255) / 256, 256, 0, stream>>>(src, dst, dinv, coef, NE);

    // layer 1: h1 = x@W1 ; agg1 = h1*dinv^2 + b1 + scatter
    gemm_kernel<128, 128, false><<<(NN + 63) / 64, 256, 0, stream>>>(x, W1, bufA, NN);
    agginit_kernel<128><<<(NN * 32 + 255) / 256, 256, 0, stream>>>(bufA, dinv, b1, bufB, NN);
    scatter_kernel<128><<<(NE * 32 + 255) / 256, 256, 0, stream>>>(src, dst, coef, bufA, bufB, NE);

    // layer 2 (relu on input read)
    gemm_kernel<128, 64, true><<<(NN + 63) / 64, 256, 0, stream>>>(bufB, W2, bufA, NN);
    agginit_kernel<64><<<(NN * 16 + 255) / 256, 256, 0, stream>>>(bufA, dinv, b2, bufB, NN);
    scatter_kernel<64><<<(NE * 16 + 255) / 256, 256, 0, stream>>>(src, dst, coef, bufA, bufB, NE);

    // layer 3 (relu on input read, no output relu)
    gemm_kernel<64, 32, true><<<(NN + 63) / 64, 256, 0, stream>>>(bufB, W3, bufA, NN);
    agginit_kernel<32><<<(NN * 8 + 255) / 256, 256, 0, stream>>>(bufA, dinv, b3, bufB, NN);
    scatter_kernel<32><<<(NE * 8 + 255) / 256, 256, 0, stream>>>(src, dst, coef, bufA, bufB, NE);

    // mean pool + epilogue
    hipMemsetAsync(sums, 0, (65536 + 2048) * sizeof(float), stream);
    cnt_kernel<<<(NN + 255) / 256, 256, 0, stream>>>(batch, cnt, NN);
    pool_kernel<<<(NN * 8 + 255) / 256, 256, 0, stream>>>(bufB, batch, sums, NN);
    final_kernel<<<1, 256, 0, stream>>>(sums, cnt, Wl, bl, targets, out);
}

// Round 2
// 922.399 us; speedup vs baseline: 5.7762x; 5.7762x over previous
//
#include <hip/hip_runtime.h>
#include <math.h>

#define NN 100000
#define NE 1600000
#define NG 2048
#define NB_SCAN 391   // (NN+255)/256

// ---------------- degree histogram (int) ----------------
__global__ __launch_bounds__(256) void deg_kernel(const int* __restrict__ dst,
                                                  int* __restrict__ degi, int E) {
    int e = blockIdx.x * 256 + threadIdx.x;
    if (e < E) atomicAdd(&degi[dst[e]], 1);
}

__global__ __launch_bounds__(256) void dinv_kernel(const int* __restrict__ degi,
                                                   float* __restrict__ dinv, int N) {
    int i = blockIdx.x * 256 + threadIdx.x;
    if (i < N) dinv[i] = rsqrtf((float)degi[i] + 1.0f);
}

// ---------------- exclusive scan (3 kernels) ----------------
__global__ __launch_bounds__(256) void scan1_kernel(const int* __restrict__ degi,
                                                    int* __restrict__ rowptr,
                                                    int* __restrict__ btot, int N) {
    __shared__ int sm[256];
    int t = threadIdx.x, n = blockIdx.x * 256 + t;
    int v = (n < N) ? degi[n] : 0;
    sm[t] = v;
    __syncthreads();
    for (int off = 1; off < 256; off <<= 1) {
        int add = (t >= off) ? sm[t - off] : 0;
        __syncthreads();
        sm[t] += add;
        __syncthreads();
    }
    if (n < N) rowptr[n] = sm[t] - v;       // intra-block exclusive
    if (t == 255) btot[blockIdx.x] = sm[255];
}

__global__ __launch_bounds__(512) void scan2_kernel(int* __restrict__ btot, int NB) {
    __shared__ int sm[512];
    int t = threadIdx.x;
    int v = (t < NB) ? btot[t] : 0;
    sm[t] = v;
    __syncthreads();
    for (int off = 1; off < 512; off <<= 1) {
        int add = (t >= off) ? sm[t - off] : 0;
        __syncthreads();
        sm[t] += add;
        __syncthreads();
    }
    if (t < NB) btot[t] = sm[t] - v;        // exclusive block offsets
}

__global__ __launch_bounds__(256) void scan3_kernel(int* __restrict__ rowptr,
                                                    const int* __restrict__ btot,
                                                    const int* __restrict__ degi, int N) {
    int n = blockIdx.x * 256 + threadIdx.x;
    if (n < N) {
        int r = rowptr[n] + btot[blockIdx.x];
        rowptr[n] = r;
        if (n == N - 1) rowptr[N] = r + degi[n];   // total = NE
    }
}

// ---------------- CSR bucket fill ----------------
__global__ __launch_bounds__(256) void fill_kernel(const int* __restrict__ src,
                                                   const int* __restrict__ dst,
                                                   const int* __restrict__ rowptr,
                                                   int* __restrict__ fill,
                                                   int* __restrict__ csr_src, int E) {
    int e = blockIdx.x * 256 + threadIdx.x;
    if (e < E) {
        int d = dst[e];
        int pos = atomicAdd(&fill[d], 1);
        csr_src[rowptr[d] + pos] = src[e];
    }
}

// ---------------- dense: out[n,:] = ((relu?)in[n,:] @ W) * dinv[n] ----------------
template<int FIN, int FOUT, bool RELU_IN>
__global__ __launch_bounds__(256) void gemm_kernel(const float* __restrict__ in,
                                                   const float* __restrict__ W,
                                                   const float* __restrict__ dinv,
                                                   float* __restrict__ out, int N) {
    constexpr int NPB = 256 / FOUT;      // rows in flight
    constexpr int ROWS = 64;             // rows per block
    __shared__ float Wl[FIN * FOUT];
    __shared__ float xr[NPB][FIN];
    const int t = threadIdx.x;
    for (int i = t; i < FIN * FOUT; i += 256) Wl[i] = W[i];
    const int f  = t % FOUT;
    const int ns = t / FOUT;
    const int base = blockIdx.x * ROWS;
    for (int n0 = 0; n0 < ROWS; n0 += NPB) {
        __syncthreads();                 // first pass also covers Wl
        for (int i = t; i < NPB * FIN; i += 256) {
            int nn = base + n0 + i / FIN;
            float v = (nn < N) ? in[(size_t)nn * FIN + (i % FIN)] : 0.0f;
            if (RELU_IN) v = fmaxf(v, 0.0f);
            xr[i / FIN][i % FIN] = v;
        }
        __syncthreads();
        float acc = 0.0f;
#pragma unroll
        for (int k = 0; k < FIN; ++k)
            acc = fmaf(xr[ns][k], Wl[k * FOUT + f], acc);
        int n = base + n0 + ns;
        if (n < N) out[(size_t)n * FOUT + f] = acc * dinv[n];   // row-scaled hs
    }
}

// ---------------- gather-aggregate: agg[n] = dinv[n]*(hs[n] + sum_e hs[src]) + b ----------------
template<int F>
__global__ __launch_bounds__(256) void agg_kernel(const int* __restrict__ rowptr,
                                                  const int* __restrict__ csr_src,
                                                  const float* __restrict__ hs,
                                                  const float* __restrict__ dinv,
                                                  const float* __restrict__ b,
                                                  float* __restrict__ agg, int N) {
    constexpr int TPN = F / 4;           // lanes per node (float4 each)
    constexpr int NPB = 256 / TPN;       // nodes per block
    int n = blockIdx.x * NPB + threadIdx.x / TPN;
    int lane = threadIdx.x % TPN;
    if (n >= N) return;
    int row = rowptr[n], end = rowptr[n + 1];
    float4 acc = *(const float4*)(hs + (size_t)n * F + lane * 4);  // self term
    int s_next = (row < end) ? csr_src[row] : 0;
    for (int j = row; j < end; ++j) {
        int s = s_next;
        if (j + 1 < end) s_next = csr_src[j + 1];   // prefetch next index
        const float4 hv = *(const float4*)(hs + (size_t)s * F + lane * 4);
        acc.x += hv.x; acc.y += hv.y; acc.z += hv.z; acc.w += hv.w;
    }
    float c = dinv[n];
    const float4 bv = *(const float4*)(b + lane * 4);
    float4 o;
    o.x = fmaf(acc.x, c, bv.x);
    o.y = fmaf(acc.y, c, bv.y);
    o.z = fmaf(acc.z, c, bv.z);
    o.w = fmaf(acc.w, c, bv.w);
    *(float4*)(agg + (size_t)n * F + lane * 4) = o;
}

// ---------------- pooling ----------------
__global__ __launch_bounds__(256) void cnt_kernel(const int* __restrict__ batch,
                                                  float* __restrict__ cnt, int N) {
    int i = blockIdx.x * 256 + threadIdx.x;
    if (i < N) atomicAdd(&cnt[batch[i]], 1.0f);
}

__global__ __launch_bounds__(256) void pool_kernel(const float* __restrict__ h,
                                                   const int* __restrict__ batch,
                                                   float* __restrict__ sums, int N) {
    int tid = blockIdx.x * 256 + threadIdx.x;
    int n = tid / 8, r = tid % 8;
    if (n >= N) return;
    int g = batch[n];
    const float4 hv = *(const float4*)(h + (size_t)n * 32 + r * 4);
    float* o = sums + (size_t)g * 32 + r * 4;
    atomicAdd(o + 0, hv.x);
    atomicAdd(o + 1, hv.y);
    atomicAdd(o + 2, hv.z);
    atomicAdd(o + 3, hv.w);
}

// ---------------- epilogue: logits, sigmoid, BCE mean (one block) ----------------
__global__ __launch_bounds__(256) void final_kernel(const float* __restrict__ sums,
                                                    const float* __restrict__ cnt,
                                                    const float* __restrict__ Wl,
                                                    const float* __restrict__ bl,
                                                    const int* __restrict__ targets,
                                                    float* __restrict__ out) {
    __shared__ float red[256];
    float lsum = 0.0f;
    for (int g = threadIdx.x; g < NG; g += 256) {
        float c = fmaxf(cnt[g], 1.0f);
        float acc = bl[0];
#pragma unroll
        for (int k = 0; k < 32; ++k)
            acc = fmaf(sums[g * 32 + k] / c, Wl[k], acc);
        out[g] = 1.0f / (1.0f + expf(-acc));
        float y = (float)targets[g];
        lsum += fmaxf(acc, 0.0f) - acc * y + log1pf(expf(-fabsf(acc)));
    }
    red[threadIdx.x] = lsum;
    __syncthreads();
    for (int s = 128; s > 0; s >>= 1) {
        if (threadIdx.x < s) red[threadIdx.x] += red[threadIdx.x + s];
        __syncthreads();
    }
    if (threadIdx.x == 0) out[NG] = red[0] / (float)NG;
}

extern "C" void kernel_launch(void* const* d_in, const int* in_sizes, int n_in,
                              void* d_out, int out_size, void* d_ws, size_t ws_size,
                              hipStream_t stream) {
    const float* x       = (const float*)d_in[0];
    const int*   ei      = (const int*)d_in[1];
    const int*   batch   = (const int*)d_in[2];
    const int*   targets = (const int*)d_in[3];
    const float* W1 = (const float*)d_in[4];
    const float* b1 = (const float*)d_in[5];
    const float* W2 = (const float*)d_in[6];
    const float* b2 = (const float*)d_in[7];
    const float* W3 = (const float*)d_in[8];
    const float* b3 = (const float*)d_in[9];
    const float* Wl = (const float*)d_in[10];
    const float* bl = (const float*)d_in[11];
    float* out = (float*)d_out;
    float* ws  = (float*)d_ws;

    const int* src = ei;
    const int* dst = ei + NE;

    // workspace layout (4B elems): total 27,468,800 -> ~109.9 MB
    float* dinv    = ws;                          // 100352
    int*   rowptr  = (int*)(ws + 100352);         // 100352 (needs NN+1)
    int*   csr_src = (int*)(ws + 200704);         // 1600512
    float* bufA    = ws + 1801216;                // 12.8M  (hs)
    float* bufB    = ws + 14601216;               // 12.8M  (agg)
    float* sums    = ws + 27401216;               // 65536
    float* cnt     = sums + 65536;                // 2048
    // transient scratch overlaid on bufB (dead before agg1 writes bufB):
    int*   degi = (int*)bufB;                     // 100352
    int*   fill = degi + 100352;                  // 100352
    int*   btot = fill + 100352;                  // 512

    // ---- build CSR (by dst) + dinv ----
    hipMemsetAsync(degi, 0, (size_t)(100352 * 2 + 512) * 4, stream);
    deg_kernel<<<(NE + 255) / 256, 256, 0, stream>>>(dst, degi, NE);
    dinv_kernel<<<(NN + 255) / 256, 256, 0, stream>>>(degi, dinv, NN);
    scan1_kernel<<<NB_SCAN, 256, 0, stream>>>(degi, rowptr, btot, NN);
    scan2_kernel<<<1, 512, 0, stream>>>(btot, NB_SCAN);
    scan3_kernel<<<NB_SCAN, 256, 0, stream>>>(rowptr, btot, degi, NN);
    fill_kernel<<<(NE + 255) / 256, 256, 0, stream>>>(src, dst, rowptr, fill, csr_src, NE);

    // ---- layer 1: hs1 = (x@W1)*dinv ; agg1 = dinv*(hs1 + gather) + b1 ----
    gemm_kernel<128, 128, false><<<(NN + 63) / 64, 256, 0, stream>>>(x, W1, dinv, bufA, NN);
    agg_kernel<128><<<(NN + 7) / 8, 256, 0, stream>>>(rowptr, csr_src, bufA, dinv, b1, bufB, NN);

    // ---- layer 2 (relu on GEMM input read) ----
    gemm_kernel<128, 64, true><<<(NN + 63) / 64, 256, 0, stream>>>(bufB, W2, dinv, bufA, NN);
    agg_kernel<64><<<(NN + 15) / 16, 256, 0, stream>>>(rowptr, csr_src, bufA, dinv, b2, bufB, NN);

    // ---- layer 3 ----
    gemm_kernel<64, 32, true><<<(NN + 63) / 64, 256, 0, stream>>>(bufB, W3, dinv, bufA, NN);
    agg_kernel<32><<<(NN + 31) / 32, 256, 0, stream>>>(rowptr, csr_src, bufA, dinv, b3, bufB, NN);

    // ---- mean pool + epilogue ----
    hipMemsetAsync(sums, 0, (65536 + 2048) * sizeof(float), stream);
    cnt_kernel<<<(NN + 255) / 256, 256, 0, stream>>>(batch, cnt, NN);
    pool_kernel<<<(NN * 8 + 255) / 256, 256, 0, stream>>>(bufB, batch, sums, NN);
    final_kernel<<<1, 256, 0, stream>>>(sums, cnt, Wl, bl, targets, out);
}

// Round 3
// 498.327 us; speedup vs baseline: 10.6917x; 1.8510x over previous
//
#include <hip/hip_runtime.h>
#include <math.h>

#define NN 100000
#define NE 1600000
#define NG 2048
#define NB_SCAN 391   // (NN+255)/256

typedef __attribute__((ext_vector_type(8))) short short8;
typedef __attribute__((ext_vector_type(8))) __bf16 bf16x8;
typedef __attribute__((ext_vector_type(4))) float f32x4;

__device__ __forceinline__ unsigned short f2bf(float f) {       // RNE, finite inputs
    unsigned int u = __float_as_uint(f);
    return (unsigned short)((u + 0x7FFFu + ((u >> 16) & 1u)) >> 16);
}
__device__ __forceinline__ float bf2f(unsigned short s) {
    return __uint_as_float(((unsigned int)s) << 16);
}

// ---------------- CSR build ----------------
__global__ __launch_bounds__(256) void deg_kernel(const int* __restrict__ dst,
                                                  int* __restrict__ degi, int E) {
    int e = blockIdx.x * 256 + threadIdx.x;
    if (e < E) atomicAdd(&degi[dst[e]], 1);
}

__global__ __launch_bounds__(256) void dinv_kernel(const int* __restrict__ degi,
                                                   float* __restrict__ dinv, int N) {
    int i = blockIdx.x * 256 + threadIdx.x;
    if (i < N) dinv[i] = rsqrtf((float)degi[i] + 1.0f);
}

__global__ __launch_bounds__(256) void scan1_kernel(const int* __restrict__ degi,
                                                    int* __restrict__ rowptr,
                                                    int* __restrict__ btot, int N) {
    __shared__ int sm[256];
    int t = threadIdx.x, n = blockIdx.x * 256 + t;
    int v = (n < N) ? degi[n] : 0;
    sm[t] = v;
    __syncthreads();
    for (int off = 1; off < 256; off <<= 1) {
        int add = (t >= off) ? sm[t - off] : 0;
        __syncthreads();
        sm[t] += add;
        __syncthreads();
    }
    if (n < N) rowptr[n] = sm[t] - v;
    if (t == 255) btot[blockIdx.x] = sm[255];
}

__global__ __launch_bounds__(512) void scan2_kernel(int* __restrict__ btot, int NB) {
    __shared__ int sm[512];
    int t = threadIdx.x;
    int v = (t < NB) ? btot[t] : 0;
    sm[t] = v;
    __syncthreads();
    for (int off = 1; off < 512; off <<= 1) {
        int add = (t >= off) ? sm[t - off] : 0;
        __syncthreads();
        sm[t] += add;
        __syncthreads();
    }
    if (t < NB) btot[t] = sm[t] - v;
}

__global__ __launch_bounds__(256) void scan3_kernel(int* __restrict__ rowptr,
                                                    const int* __restrict__ btot,
                                                    const int* __restrict__ degi, int N) {
    int n = blockIdx.x * 256 + threadIdx.x;
    if (n < N) {
        int r = rowptr[n] + btot[blockIdx.x];
        rowptr[n] = r;
        if (n == N - 1) rowptr[N] = r + degi[n];
    }
}

__global__ __launch_bounds__(256) void fill_kernel(const int* __restrict__ src,
                                                   const int* __restrict__ dst,
                                                   const int* __restrict__ rowptr,
                                                   int* __restrict__ fill,
                                                   int* __restrict__ csr_src, int E) {
    int e = blockIdx.x * 256 + threadIdx.x;
    if (e < E) {
        int d = dst[e];
        int pos = atomicAdd(&fill[d], 1);
        csr_src[rowptr[d] + pos] = src[e];
    }
}

// ---------------- weight fp32 -> bf16 ----------------
__global__ __launch_bounds__(256) void w2bf_kernel(const float* __restrict__ in,
                                                   unsigned short* __restrict__ out, int n) {
    int i = blockIdx.x * 256 + threadIdx.x;
    if (i < n) out[i] = f2bf(in[i]);
}

// ---------------- MFMA GEMM: hs[n,:] = ((relu?)A[n,:] @ W) * dinv[n], bf16 out ----------------
// Per-wave: fixed 16-col n-tile (W frags in regs), grid-stride over 16-row m-tiles.
// Layouts [m89-verified]: A: m=lane&15, k=quad*8+j ; B: n=lane&15, k=quad*8+j ;
//                         C/D: col=lane&15, row=quad*4+reg.
template<int FIN, int FOUT, bool RELU_IN, bool A_BF16>
__global__ __launch_bounds__(256) void mfma_gemm(const void* __restrict__ in_,
                                                 const unsigned short* __restrict__ Wb,
                                                 const float* __restrict__ dinv,
                                                 unsigned short* __restrict__ out,
                                                 int N, int nwaves) {
    constexpr int NT = FOUT / 16;
    constexpr int KS = FIN / 32;
    const int lane = threadIdx.x & 63;
    const int wid  = (blockIdx.x * 256 + threadIdx.x) >> 6;
    const int ntile = wid % NT;
    const int col  = (lane & 15) + ntile * 16;
    const int quad = lane >> 4;
    const int koff = quad * 8;

    short8 bfrag[KS];
#pragma unroll
    for (int ks = 0; ks < KS; ++ks)
#pragma unroll
        for (int j = 0; j < 8; ++j)
            bfrag[ks][j] = (short)Wb[(ks * 32 + koff + j) * FOUT + col];

    const int MT = N / 16;                 // N == 100000 -> exact
    const int mstride = nwaves / NT;
    for (int mt = wid / NT; mt < MT; mt += mstride) {
        const int row = mt * 16 + (lane & 15);
        short8 afrag[KS];
        if (A_BF16) {
            const unsigned short* A = (const unsigned short*)in_ + (size_t)row * FIN + koff;
#pragma unroll
            for (int ks = 0; ks < KS; ++ks) {
                short8 a = *(const short8*)(A + ks * 32);
                if (RELU_IN) {
#pragma unroll
                    for (int j = 0; j < 8; ++j)
                        a[j] = (short)(((unsigned short)a[j] & 0x8000u) ? 0 : (unsigned short)a[j]);
                }
                afrag[ks] = a;
            }
        } else {
            const float* A = (const float*)in_ + (size_t)row * FIN + koff;
#pragma unroll
            for (int ks = 0; ks < KS; ++ks) {
                f32x4 v0 = *(const f32x4*)(A + ks * 32);
                f32x4 v1 = *(const f32x4*)(A + ks * 32 + 4);
#pragma unroll
                for (int j = 0; j < 4; ++j) {
                    float a0 = v0[j], a1 = v1[j];
                    if (RELU_IN) { a0 = fmaxf(a0, 0.f); a1 = fmaxf(a1, 0.f); }
                    afrag[ks][j]     = (short)f2bf(a0);
                    afrag[ks][j + 4] = (short)f2bf(a1);
                }
            }
        }
        f32x4 acc = {0.f, 0.f, 0.f, 0.f};
#pragma unroll
        for (int ks = 0; ks < KS; ++ks)
            acc = __builtin_amdgcn_mfma_f32_16x16x32_bf16(
                __builtin_bit_cast(bf16x8, afrag[ks]),
                __builtin_bit_cast(bf16x8, bfrag[ks]), acc, 0, 0, 0);
#pragma unroll
        for (int r = 0; r < 4; ++r) {
            int orow = mt * 16 + quad * 4 + r;
            out[(size_t)orow * FOUT + col] = f2bf(acc[r] * dinv[orow]);
        }
    }
}

// ---------------- gather-aggregate: agg[n] = dinv[n]*(hs[n] + sum_e hs[src]) + b ----------------
template<int F, bool OUT_BF16>
__global__ __launch_bounds__(256) void agg_kernel(const int* __restrict__ rowptr,
                                                  const int* __restrict__ csr_src,
                                                  const unsigned short* __restrict__ hs,
                                                  const float* __restrict__ dinv,
                                                  const float* __restrict__ b,
                                                  void* __restrict__ aggout, int N) {
    constexpr int TPN = F / 8;           // lanes per node (8 bf16 = 16B each)
    constexpr int NPB = 256 / TPN;
    int n = blockIdx.x * NPB + threadIdx.x / TPN;
    int c8 = (threadIdx.x % TPN) * 8;
    if (n >= N) return;
    int row = rowptr[n], end = rowptr[n + 1];
    float acc[8];
    {
        short8 h = *(const short8*)(hs + (size_t)n * F + c8);   // self term
#pragma unroll
        for (int j = 0; j < 8; ++j) acc[j] = bf2f((unsigned short)h[j]);
    }
    int s_next = (row < end) ? csr_src[row] : 0;
    for (int jj = row; jj < end; ++jj) {
        int s = s_next;
        if (jj + 1 < end) s_next = csr_src[jj + 1];
        short8 h = *(const short8*)(hs + (size_t)s * F + c8);
#pragma unroll
        for (int j = 0; j < 8; ++j) acc[j] += bf2f((unsigned short)h[j]);
    }
    float c = dinv[n];
    if (OUT_BF16) {
        short8 o;
#pragma unroll
        for (int j = 0; j < 8; ++j) o[j] = (short)f2bf(fmaf(acc[j], c, b[c8 + j]));
        *(short8*)((unsigned short*)aggout + (size_t)n * F + c8) = o;
    } else {
        f32x4 o0, o1;
#pragma unroll
        for (int j = 0; j < 4; ++j) {
            o0[j] = fmaf(acc[j], c, b[c8 + j]);
            o1[j] = fmaf(acc[j + 4], c, b[c8 + j + 4]);
        }
        float* of = (float*)aggout + (size_t)n * F + c8;
        *(f32x4*)of = o0;
        *(f32x4*)(of + 4) = o1;
    }
}

// ---------------- per-graph node ranges (batch is sorted) ----------------
__global__ __launch_bounds__(256) void grange_kernel(const int* __restrict__ batch,
                                                     int* __restrict__ gstart) {
    int g = blockIdx.x * 256 + threadIdx.x;
    if (g > NG) return;
    if (g == NG) { gstart[g] = NN; return; }
    int lo = 0, hi = NN;
    while (lo < hi) { int mid = (lo + hi) >> 1; if (batch[mid] < g) lo = mid + 1; else hi = mid; }
    gstart[g] = lo;
}

// ---------------- pool: pooled[g,:] = mean of h rows in [gstart[g], gstart[g+1]) ----------------
__global__ __launch_bounds__(256) void pool2_kernel(const float* __restrict__ h,
                                                    const int* __restrict__ gstart,
                                                    float* __restrict__ pooled) {
    __shared__ float sm[256];
    int g = blockIdx.x;
    int s = gstart[g], e = gstart[g + 1];
    int f = threadIdx.x & 31, slot = threadIdx.x >> 5;
    float acc = 0.f;
    for (int n = s + slot; n < e; n += 8) acc += h[(size_t)n * 32 + f];
    sm[threadIdx.x] = acc;
    __syncthreads();
    if (threadIdx.x < 128) sm[threadIdx.x] += sm[threadIdx.x + 128];
    __syncthreads();
    if (threadIdx.x < 64) sm[threadIdx.x] += sm[threadIdx.x + 64];
    __syncthreads();
    if (threadIdx.x < 32) {
        float v = sm[threadIdx.x] + sm[threadIdx.x + 32];
        float cntf = fmaxf((float)(e - s), 1.0f);
        pooled[(size_t)g * 32 + f] = v / cntf;
    }
}

// ---------------- epilogue ----------------
__global__ __launch_bounds__(256) void final_kernel(const float* __restrict__ pooled,
                                                    const float* __restrict__ Wl,
                                                    const float* __restrict__ bl,
                                                    const int* __restrict__ targets,
                                                    float* __restrict__ out) {
    __shared__ float red[256];
    float lsum = 0.0f;
    for (int g = threadIdx.x; g < NG; g += 256) {
        float acc = bl[0];
#pragma unroll
        for (int k = 0; k < 32; ++k)
            acc = fmaf(pooled[(size_t)g * 32 + k], Wl[k], acc);
        out[g] = 1.0f / (1.0f + expf(-acc));
        float y = (float)targets[g];
        lsum += fmaxf(acc, 0.0f) - acc * y + log1pf(expf(-fabsf(acc)));
    }
    red[threadIdx.x] = lsum;
    __syncthreads();
    for (int s = 128; s > 0; s >>= 1) {
        if (threadIdx.x < s) red[threadIdx.x] += red[threadIdx.x + s];
        __syncthreads();
    }
    if (threadIdx.x == 0) out[NG] = red[0] / (float)NG;
}

extern "C" void kernel_launch(void* const* d_in, const int* in_sizes, int n_in,
                              void* d_out, int out_size, void* d_ws, size_t ws_size,
                              hipStream_t stream) {
    const float* x       = (const float*)d_in[0];
    const int*   ei      = (const int*)d_in[1];
    const int*   batch   = (const int*)d_in[2];
    const int*   targets = (const int*)d_in[3];
    const float* W1 = (const float*)d_in[4];
    const float* b1 = (const float*)d_in[5];
    const float* W2 = (const float*)d_in[6];
    const float* b2 = (const float*)d_in[7];
    const float* W3 = (const float*)d_in[8];
    const float* b3 = (const float*)d_in[9];
    const float* Wl = (const float*)d_in[10];
    const float* bl = (const float*)d_in[11];
    float* out = (float*)d_out;
    char*  ws  = (char*)d_ws;

    const int* src = ei;
    const int* dst = ei + NE;

    // workspace layout (byte offsets, 512B aligned) — total ~59 MB
    float*          dinv    = (float*)(ws);                    // 400,384 B
    int*            rowptr  = (int*)(ws + 400384);             // 400,384 B (NN+1)
    int*            csr_src = (int*)(ws + 800768);             // 6,400,000 B
    unsigned short* Wb1     = (unsigned short*)(ws + 7200768); //   32,768 B
    unsigned short* Wb2     = (unsigned short*)(ws + 7233536); //   16,384 B
    unsigned short* Wb3     = (unsigned short*)(ws + 7249920); //    4,096 B
    int*            gstart  = (int*)(ws + 7254016);            //    8,704 B (NG+1)
    unsigned short* hsbuf   = (unsigned short*)(ws + 7262720); // 25,600,512 B
    unsigned short* aggbuf  = (unsigned short*)(ws + 32863232);// 25,600,512 B
    float*          pooled  = (float*)(ws + 58463744);         //  262,144 B
    // transient CSR scratch overlaid on hsbuf (dead until GEMM1 writes hsbuf)
    int* degi = (int*)hsbuf;           // 100,352 ints
    int* fill = degi + 100352;         // 100,352 ints
    int* btot = fill + 100352;         // 512 ints

    // ---- CSR + dinv + graph ranges + weight converts ----
    hipMemsetAsync(degi, 0, (size_t)(100352 * 2 + 512) * 4, stream);
    deg_kernel<<<(NE + 255) / 256, 256, 0, stream>>>(dst, degi, NE);
    dinv_kernel<<<(NN + 255) / 256, 256, 0, stream>>>(degi, dinv, NN);
    scan1_kernel<<<NB_SCAN, 256, 0, stream>>>(degi, rowptr, btot, NN);
    scan2_kernel<<<1, 512, 0, stream>>>(btot, NB_SCAN);
    scan3_kernel<<<NB_SCAN, 256, 0, stream>>>(rowptr, btot, degi, NN);
    fill_kernel<<<(NE + 255) / 256, 256, 0, stream>>>(src, dst, rowptr, fill, csr_src, NE);
    grange_kernel<<<9, 256, 0, stream>>>(batch, gstart);
    w2bf_kernel<<<64, 256, 0, stream>>>(W1, Wb1, 128 * 128);
    w2bf_kernel<<<32, 256, 0, stream>>>(W2, Wb2, 128 * 64);
    w2bf_kernel<<<8, 256, 0, stream>>>(W3, Wb3, 64 * 32);

    const int GB = 1024;               // 4096 waves; NT in {8,4,2} all divide
    const int NWAVES = GB * 4;

    // ---- layer 1 ----
    mfma_gemm<128, 128, false, false><<<GB, 256, 0, stream>>>(x, Wb1, dinv, hsbuf, NN, NWAVES);
    agg_kernel<128, true><<<(NN + 15) / 16, 256, 0, stream>>>(rowptr, csr_src, hsbuf, dinv, b1, aggbuf, NN);

    // ---- layer 2 ----
    mfma_gemm<128, 64, true, true><<<GB, 256, 0, stream>>>(aggbuf, Wb2, dinv, hsbuf, NN, NWAVES);
    agg_kernel<64, true><<<(NN + 31) / 32, 256, 0, stream>>>(rowptr, csr_src, hsbuf, dinv, b2, aggbuf, NN);

    // ---- layer 3 (agg out fp32 for pooling) ----
    mfma_gemm<64, 32, true, true><<<GB, 256, 0, stream>>>(aggbuf, Wb3, dinv, hsbuf, NN, NWAVES);
    agg_kernel<32, false><<<(NN + 63) / 64, 256, 0, stream>>>(rowptr, csr_src, hsbuf, dinv, b3, aggbuf, NN);

    // ---- pool + epilogue ----
    pool2_kernel<<<NG, 256, 0, stream>>>((const float*)aggbuf, gstart, pooled);
    final_kernel<<<1, 256, 0, stream>>>(pooled, Wl, bl, targets, out);
}

// Round 4
// 367.461 us; speedup vs baseline: 14.4994x; 1.3561x over previous
//
#include <hip/hip_runtime.h>
#include <math.h>

#define NN 100000
#define NE 1600000
#define NG 2048
#define NBUK 391     // ceil(NN/256) dst-buckets, bucket = dst >> 8
#define SLOT 6144    // per-bucket capacity: mean 4096 + 32 sigma
#define CHUNK 8192   // edges per bin block

typedef __attribute__((ext_vector_type(8))) short short8;
typedef __attribute__((ext_vector_type(8))) __bf16 bf16x8;
typedef __attribute__((ext_vector_type(4))) float f32x4;

__device__ __forceinline__ unsigned short f2bf(float f) {       // RNE, finite inputs
    unsigned int u = __float_as_uint(f);
    return (unsigned short)((u + 0x7FFFu + ((u >> 16) & 1u)) >> 16);
}
__device__ __forceinline__ float bf2f(unsigned short s) {
    return __uint_as_float(((unsigned int)s) << 16);
}

// ---------------- pass 1: bin edges by dst>>8, bucket-sorted block appends ----------------
__global__ __launch_bounds__(256) void bin_kernel(const int* __restrict__ src,
                                                  const int* __restrict__ dst,
                                                  int* __restrict__ gcnt,
                                                  int* __restrict__ bucket_data, int E) {
    __shared__ int cnt[512];                 // padded scan array
    __shared__ int offs[NBUK];
    __shared__ int cnt2[NBUK];
    __shared__ int gb[NBUK];
    __shared__ int packB[CHUNK];
    __shared__ unsigned short bktB[CHUNK];
    const int t = threadIdx.x;
    const int E0 = blockIdx.x * CHUNK;
    const int valid = min(CHUNK, E - E0);
    cnt[t] = 0; cnt[t + 256] = 0;
    for (int i = t; i < NBUK; i += 256) cnt2[i] = 0;
    __syncthreads();
    // A: count buckets
    for (int i = t; i < valid; i += 256)
        atomicAdd(&cnt[dst[E0 + i] >> 8], 1);
    __syncthreads();
    int o0 = cnt[t], o1 = cnt[t + 256];
    // B: inclusive Hillis-Steele scan over 512 (2 elems/thread)
    for (int off = 1; off < 512; off <<= 1) {
        int a0 = (t >= off) ? cnt[t - off] : 0;
        int a1 = (t + 256 >= off) ? cnt[t + 256 - off] : 0;
        __syncthreads();
        cnt[t] += a0; cnt[t + 256] += a1;
        __syncthreads();
    }
    if (t < NBUK)       { offs[t] = cnt[t] - o0;             gb[t] = o0 ? atomicAdd(&gcnt[t], o0) : 0; }
    if (t + 256 < NBUK) { offs[t + 256] = cnt[t + 256] - o1; gb[t + 256] = o1 ? atomicAdd(&gcnt[t + 256], o1) : 0; }
    __syncthreads();
    // C: re-read edges, place bucket-sorted into LDS
    for (int i = t; i < valid; i += 256) {
        int s = src[E0 + i], d = dst[E0 + i];
        int b = d >> 8;
        int pos = offs[b] + atomicAdd(&cnt2[b], 1);
        packB[pos] = (s << 8) | (d & 255);
        bktB[pos] = (unsigned short)b;
    }
    __syncthreads();
    // D: contiguous-per-bucket append to global streams
    for (int i = t; i < valid; i += 256) {
        int b = bktB[i];
        int idx = gb[b] + (i - offs[b]);
        if (idx < SLOT) bucket_data[b * SLOT + idx] = packB[i];
    }
}

// ---------------- pass 1b: exclusive scan of bucket counts ----------------
__global__ __launch_bounds__(512) void bbase_kernel(const int* __restrict__ gcnt,
                                                    int* __restrict__ gbase) {
    __shared__ int sm[512];
    int t = threadIdx.x;
    int v = (t < NBUK) ? gcnt[t] : 0;
    sm[t] = v;
    __syncthreads();
    for (int off = 1; off < 512; off <<= 1) {
        int a = (t >= off) ? sm[t - off] : 0;
        __syncthreads();
        sm[t] += a;
        __syncthreads();
    }
    if (t < NBUK) gbase[t] = sm[t] - v;
}

// ---------------- pass 2: per-bucket CSR finalize + dinv + rowptr ----------------
__global__ __launch_bounds__(256) void csr2_kernel(const int* __restrict__ gcnt,
                                                   const int* __restrict__ gbase,
                                                   const int* __restrict__ bucket_data,
                                                   float* __restrict__ dinv,
                                                   int* __restrict__ rowptr,
                                                   int* __restrict__ csr_src) {
    __shared__ int counts[256];
    __shared__ int offs[256];
    __shared__ int counts2[256];
    const int t = threadIdx.x;
    const int b = blockIdx.x;
    const int cb = min(gcnt[b], SLOT);
    const int base = gbase[b];
    const int* bd = bucket_data + b * SLOT;
    counts[t] = 0; counts2[t] = 0;
    __syncthreads();
    for (int i = t; i < cb; i += 256) atomicAdd(&counts[bd[i] & 255], 1);
    __syncthreads();
    int c = counts[t];
    for (int off = 1; off < 256; off <<= 1) {
        int a = (t >= off) ? counts[t - off] : 0;
        __syncthreads();
        counts[t] += a;
        __syncthreads();
    }
    int excl = counts[t] - c;
    offs[t] = excl;
    int node = b * 256 + t;
    if (node < NN) {
        dinv[node] = rsqrtf((float)c + 1.0f);
        rowptr[node] = base + excl;
    }
    if (b == NBUK - 1 && t == 0) rowptr[NN] = NE;
    __syncthreads();
    for (int i = t; i < cb; i += 256) {
        int p = bd[i];
        int local = p & 255;
        int pos = atomicAdd(&counts2[local], 1);
        csr_src[base + offs[local] + pos] = p >> 8;   // p>=0, arith shift ok
    }
}

// ---------------- weight fp32 -> bf16 ----------------
__global__ __launch_bounds__(256) void w2bf_kernel(const float* __restrict__ in,
                                                   unsigned short* __restrict__ out, int n) {
    int i = blockIdx.x * 256 + threadIdx.x;
    if (i < n) out[i] = f2bf(in[i]);
}

// ---------------- MFMA GEMM: hs[n,:] = ((relu?)A[n,:] @ W) * dinv[n], bf16 out ----------------
// Layouts [m89-verified]: A: m=lane&15, k=quad*8+j ; B: n=lane&15, k=quad*8+j ;
//                         C/D: col=lane&15, row=quad*4+reg.
template<int FIN, int FOUT, bool RELU_IN, bool A_BF16>
__global__ __launch_bounds__(256) void mfma_gemm(const void* __restrict__ in_,
                                                 const unsigned short* __restrict__ Wb,
                                                 const float* __restrict__ dinv,
                                                 unsigned short* __restrict__ out,
                                                 int N, int nwaves) {
    constexpr int NT = FOUT / 16;
    constexpr int KS = FIN / 32;
    const int lane = threadIdx.x & 63;
    const int wid  = (blockIdx.x * 256 + threadIdx.x) >> 6;
    const int ntile = wid % NT;
    const int col  = (lane & 15) + ntile * 16;
    const int quad = lane >> 4;
    const int koff = quad * 8;

    short8 bfrag[KS];
#pragma unroll
    for (int ks = 0; ks < KS; ++ks)
#pragma unroll
        for (int j = 0; j < 8; ++j)
            bfrag[ks][j] = (short)Wb[(ks * 32 + koff + j) * FOUT + col];

    const int MT = N / 16;                 // N == 100000 -> exact
    const int mstride = nwaves / NT;
    for (int mt = wid / NT; mt < MT; mt += mstride) {
        const int row = mt * 16 + (lane & 15);
        short8 afrag[KS];
        if (A_BF16) {
            const unsigned short* A = (const unsigned short*)in_ + (size_t)row * FIN + koff;
#pragma unroll
            for (int ks = 0; ks < KS; ++ks) {
                short8 a = *(const short8*)(A + ks * 32);
                if (RELU_IN) {
#pragma unroll
                    for (int j = 0; j < 8; ++j)
                        a[j] = (short)(((unsigned short)a[j] & 0x8000u) ? 0 : (unsigned short)a[j]);
                }
                afrag[ks] = a;
            }
        } else {
            const float* A = (const float*)in_ + (size_t)row * FIN + koff;
#pragma unroll
            for (int ks = 0; ks < KS; ++ks) {
                f32x4 v0 = *(const f32x4*)(A + ks * 32);
                f32x4 v1 = *(const f32x4*)(A + ks * 32 + 4);
#pragma unroll
                for (int j = 0; j < 4; ++j) {
                    float a0 = v0[j], a1 = v1[j];
                    if (RELU_IN) { a0 = fmaxf(a0, 0.f); a1 = fmaxf(a1, 0.f); }
                    afrag[ks][j]     = (short)f2bf(a0);
                    afrag[ks][j + 4] = (short)f2bf(a1);
                }
            }
        }
        f32x4 acc = {0.f, 0.f, 0.f, 0.f};
#pragma unroll
        for (int ks = 0; ks < KS; ++ks)
            acc = __builtin_amdgcn_mfma_f32_16x16x32_bf16(
                __builtin_bit_cast(bf16x8, afrag[ks]),
                __builtin_bit_cast(bf16x8, bfrag[ks]), acc, 0, 0, 0);
#pragma unroll
        for (int r = 0; r < 4; ++r) {
            int orow = mt * 16 + quad * 4 + r;
            out[(size_t)orow * FOUT + col] = f2bf(acc[r] * dinv[orow]);
        }
    }
}

// ---------------- gather-aggregate: agg[n] = dinv[n]*(hs[n] + sum_e hs[src]) + b ----------------
template<int F, bool OUT_BF16>
__global__ __launch_bounds__(256) void agg_kernel(const int* __restrict__ rowptr,
                                                  const int* __restrict__ csr_src,
                                                  const unsigned short* __restrict__ hs,
                                                  const float* __restrict__ dinv,
                                                  const float* __restrict__ b,
                                                  void* __restrict__ aggout, int N) {
    constexpr int TPN = F / 8;           // lanes per node (8 bf16 = 16B each)
    constexpr int NPB = 256 / TPN;
    int n = blockIdx.x * NPB + threadIdx.x / TPN;
    int c8 = (threadIdx.x % TPN) * 8;
    if (n >= N) return;
    int row = rowptr[n], end = rowptr[n + 1];
    float acc[8];
    {
        short8 h = *(const short8*)(hs + (size_t)n * F + c8);   // self term
#pragma unroll
        for (int j = 0; j < 8; ++j) acc[j] = bf2f((unsigned short)h[j]);
    }
    int s_next = (row < end) ? csr_src[row] : 0;
    for (int jj = row; jj < end; ++jj) {
        int s = s_next;
        if (jj + 1 < end) s_next = csr_src[jj + 1];
        short8 h = *(const short8*)(hs + (size_t)s * F + c8);
#pragma unroll
        for (int j = 0; j < 8; ++j) acc[j] += bf2f((unsigned short)h[j]);
    }
    float c = dinv[n];
    if (OUT_BF16) {
        short8 o;
#pragma unroll
        for (int j = 0; j < 8; ++j) o[j] = (short)f2bf(fmaf(acc[j], c, b[c8 + j]));
        *(short8*)((unsigned short*)aggout + (size_t)n * F + c8) = o;
    } else {
        f32x4 o0, o1;
#pragma unroll
        for (int j = 0; j < 4; ++j) {
            o0[j] = fmaf(acc[j], c, b[c8 + j]);
            o1[j] = fmaf(acc[j + 4], c, b[c8 + j + 4]);
        }
        float* of = (float*)aggout + (size_t)n * F + c8;
        *(f32x4*)of = o0;
        *(f32x4*)(of + 4) = o1;
    }
}

// ---------------- per-graph node ranges (batch is sorted) ----------------
__global__ __launch_bounds__(256) void grange_kernel(const int* __restrict__ batch,
                                                     int* __restrict__ gstart) {
    int g = blockIdx.x * 256 + threadIdx.x;
    if (g > NG) return;
    if (g == NG) { gstart[g] = NN; return; }
    int lo = 0, hi = NN;
    while (lo < hi) { int mid = (lo + hi) >> 1; if (batch[mid] < g) lo = mid + 1; else hi = mid; }
    gstart[g] = lo;
}

// ---------------- pool: pooled[g,:] = mean of h rows in [gstart[g], gstart[g+1]) ----------------
__global__ __launch_bounds__(256) void pool2_kernel(const float* __restrict__ h,
                                                    const int* __restrict__ gstart,
                                                    float* __restrict__ pooled) {
    __shared__ float sm[256];
    int g = blockIdx.x;
    int s = gstart[g], e = gstart[g + 1];
    int f = threadIdx.x & 31, slot = threadIdx.x >> 5;
    float acc = 0.f;
    for (int n = s + slot; n < e; n += 8) acc += h[(size_t)n * 32 + f];
    sm[threadIdx.x] = acc;
    __syncthreads();
    if (threadIdx.x < 128) sm[threadIdx.x] += sm[threadIdx.x + 128];
    __syncthreads();
    if (threadIdx.x < 64) sm[threadIdx.x] += sm[threadIdx.x + 64];
    __syncthreads();
    if (threadIdx.x < 32) {
        float v = sm[threadIdx.x] + sm[threadIdx.x + 32];
        float cntf = fmaxf((float)(e - s), 1.0f);
        pooled[(size_t)g * 32 + f] = v / cntf;
    }
}

// ---------------- epilogue ----------------
__global__ __launch_bounds__(256) void final_kernel(const float* __restrict__ pooled,
                                                    const float* __restrict__ Wl,
                                                    const float* __restrict__ bl,
                                                    const int* __restrict__ targets,
                                                    float* __restrict__ out) {
    __shared__ float red[256];
    float lsum = 0.0f;
    for (int g = threadIdx.x; g < NG; g += 256) {
        float acc = bl[0];
#pragma unroll
        for (int k = 0; k < 32; ++k)
            acc = fmaf(pooled[(size_t)g * 32 + k], Wl[k], acc);
        out[g] = 1.0f / (1.0f + expf(-acc));
        float y = (float)targets[g];
        lsum += fmaxf(acc, 0.0f) - acc * y + log1pf(expf(-fabsf(acc)));
    }
    red[threadIdx.x] = lsum;
    __syncthreads();
    for (int s = 128; s > 0; s >>= 1) {
        if (threadIdx.x < s) red[threadIdx.x] += red[threadIdx.x + s];
        __syncthreads();
    }
    if (threadIdx.x == 0) out[NG] = red[0] / (float)NG;
}

extern "C" void kernel_launch(void* const* d_in, const int* in_sizes, int n_in,
                              void* d_out, int out_size, void* d_ws, size_t ws_size,
                              hipStream_t stream) {
    const float* x       = (const float*)d_in[0];
    const int*   ei      = (const int*)d_in[1];
    const int*   batch   = (const int*)d_in[2];
    const int*   targets = (const int*)d_in[3];
    const float* W1 = (const float*)d_in[4];
    const float* b1 = (const float*)d_in[5];
    const float* W2 = (const float*)d_in[6];
    const float* b2 = (const float*)d_in[7];
    const float* W3 = (const float*)d_in[8];
    const float* b3 = (const float*)d_in[9];
    const float* Wl = (const float*)d_in[10];
    const float* bl = (const float*)d_in[11];
    float* out = (float*)d_out;
    char*  ws  = (char*)d_ws;

    const int* src = ei;
    const int* dst = ei + NE;

    // workspace layout (byte offsets, 512B aligned) — total ~68.3 MB
    float*          dinv    = (float*)(ws);                    //    400,384 B
    int*            rowptr  = (int*)(ws + 400384);             //    400,384 B (NN+1)
    int*            csr_src = (int*)(ws + 800768);             //  6,400,512 B
    unsigned short* Wb1     = (unsigned short*)(ws + 7201280); //     32,768 B
    unsigned short* Wb2     = (unsigned short*)(ws + 7234048); //     16,384 B
    unsigned short* Wb3     = (unsigned short*)(ws + 7250432); //      4,096 B
    int*            gstart  = (int*)(ws + 7254528);            //      8,704 B (NG+1)
    unsigned short* hsbuf   = (unsigned short*)(ws + 7263232); // 25,600,512 B
    unsigned short* aggbuf  = (unsigned short*)(ws + 32863744);// 25,600,512 B
    float*          pooled  = (float*)(ws + 58464256);         //    262,144 B
    int*            bdata   = (int*)(ws + 58726400);           //  9,609,216 B (391*6144*4)
    int*            gcnt    = (int*)(ws + 68335616);           //      2,048 B
    int*            gbase   = (int*)(ws + 68337664);           //      2,048 B

    // ---- CSR build (bucketed, no global scatter-atomics) ----
    hipMemsetAsync(gcnt, 0, 2048, stream);
    bin_kernel<<<(NE + CHUNK - 1) / CHUNK, 256, 0, stream>>>(src, dst, gcnt, bdata, NE);
    bbase_kernel<<<1, 512, 0, stream>>>(gcnt, gbase);
    csr2_kernel<<<NBUK, 256, 0, stream>>>(gcnt, gbase, bdata, dinv, rowptr, csr_src);

    // ---- independent small setup ----
    grange_kernel<<<9, 256, 0, stream>>>(batch, gstart);
    w2bf_kernel<<<64, 256, 0, stream>>>(W1, Wb1, 128 * 128);
    w2bf_kernel<<<32, 256, 0, stream>>>(W2, Wb2, 128 * 64);
    w2bf_kernel<<<8, 256, 0, stream>>>(W3, Wb3, 64 * 32);

    const int GB = 1024;               // 4096 waves; NT in {8,4,2} all divide
    const int NWAVES = GB * 4;

    // ---- layer 1 ----
    mfma_gemm<128, 128, false, false><<<GB, 256, 0, stream>>>(x, Wb1, dinv, hsbuf, NN, NWAVES);
    agg_kernel<128, true><<<(NN + 15) / 16, 256, 0, stream>>>(rowptr, csr_src, hsbuf, dinv, b1, aggbuf, NN);

    // ---- layer 2 ----
    mfma_gemm<128, 64, true, true><<<GB, 256, 0, stream>>>(aggbuf, Wb2, dinv, hsbuf, NN, NWAVES);
    agg_kernel<64, true><<<(NN + 31) / 32, 256, 0, stream>>>(rowptr, csr_src, hsbuf, dinv, b2, aggbuf, NN);

    // ---- layer 3 (agg out fp32 for pooling) ----
    mfma_gemm<64, 32, true, true><<<GB, 256, 0, stream>>>(aggbuf, Wb3, dinv, hsbuf, NN, NWAVES);
    agg_kernel<32, false><<<(NN + 63) / 64, 256, 0, stream>>>(rowptr, csr_src, hsbuf, dinv, b3, aggbuf, NN);

    // ---- pool + epilogue ----
    pool2_kernel<<<NG, 256, 0, stream>>>((const float*)aggbuf, gstart, pooled);
    final_kernel<<<1, 256, 0, stream>>>(pooled, Wl, bl, targets, out);
}

// Round 5
// 359.045 us; speedup vs baseline: 14.8392x; 1.0234x over previous
//
#include <hip/hip_runtime.h>
#include <math.h>

#define NN 100000
#define NE 1600000
#define NG 2048
#define NBUK 391     // ceil(NN/256) dst-buckets, bucket = dst >> 8
#define SLOT 6144    // per-bucket capacity: mean 4096 + 32 sigma
#define CHUNK 8192   // edges per bin block

typedef __attribute__((ext_vector_type(8))) short short8;
typedef __attribute__((ext_vector_type(8))) __bf16 bf16x8;
typedef __attribute__((ext_vector_type(4))) float f32x4;

__device__ __forceinline__ unsigned short f2bf(float f) {       // RNE, finite inputs
    unsigned int u = __float_as_uint(f);
    return (unsigned short)((u + 0x7FFFu + ((u >> 16) & 1u)) >> 16);
}
__device__ __forceinline__ float bf2f(unsigned short s) {
    return __uint_as_float(((unsigned int)s) << 16);
}

// ---------------- pass 1: bin edges by dst>>8, bucket-sorted block appends ----------------
__global__ __launch_bounds__(256) void bin_kernel(const int* __restrict__ src,
                                                  const int* __restrict__ dst,
                                                  int* __restrict__ gcnt,
                                                  int* __restrict__ bucket_data, int E) {
    __shared__ int cnt[512];                 // padded scan array
    __shared__ int offs[NBUK];
    __shared__ int cnt2[NBUK];
    __shared__ int gb[NBUK];
    __shared__ int packB[CHUNK];
    __shared__ unsigned short bktB[CHUNK];
    const int t = threadIdx.x;
    const int E0 = blockIdx.x * CHUNK;
    const int valid = min(CHUNK, E - E0);
    cnt[t] = 0; cnt[t + 256] = 0;
    for (int i = t; i < NBUK; i += 256) cnt2[i] = 0;
    __syncthreads();
    // A: count buckets
    for (int i = t; i < valid; i += 256)
        atomicAdd(&cnt[dst[E0 + i] >> 8], 1);
    __syncthreads();
    int o0 = cnt[t], o1 = cnt[t + 256];
    // B: inclusive Hillis-Steele scan over 512 (2 elems/thread)
    for (int off = 1; off < 512; off <<= 1) {
        int a0 = (t >= off) ? cnt[t - off] : 0;
        int a1 = (t + 256 >= off) ? cnt[t + 256 - off] : 0;
        __syncthreads();
        cnt[t] += a0; cnt[t + 256] += a1;
        __syncthreads();
    }
    if (t < NBUK)       { offs[t] = cnt[t] - o0;             gb[t] = o0 ? atomicAdd(&gcnt[t], o0) : 0; }
    if (t + 256 < NBUK) { offs[t + 256] = cnt[t + 256] - o1; gb[t + 256] = o1 ? atomicAdd(&gcnt[t + 256], o1) : 0; }
    __syncthreads();
    // C: re-read edges, place bucket-sorted into LDS
    for (int i = t; i < valid; i += 256) {
        int s = src[E0 + i], d = dst[E0 + i];
        int b = d >> 8;
        int pos = offs[b] + atomicAdd(&cnt2[b], 1);
        packB[pos] = (s << 8) | (d & 255);
        bktB[pos] = (unsigned short)b;
    }
    __syncthreads();
    // D: contiguous-per-bucket append to global streams
    for (int i = t; i < valid; i += 256) {
        int b = bktB[i];
        int idx = gb[b] + (i - offs[b]);
        if (idx < SLOT) bucket_data[b * SLOT + idx] = packB[i];
    }
}

// ---------------- pass 1b: exclusive scan of bucket counts ----------------
__global__ __launch_bounds__(512) void bbase_kernel(const int* __restrict__ gcnt,
                                                    int* __restrict__ gbase) {
    __shared__ int sm[512];
    int t = threadIdx.x;
    int v = (t < NBUK) ? gcnt[t] : 0;
    sm[t] = v;
    __syncthreads();
    for (int off = 1; off < 512; off <<= 1) {
        int a = (t >= off) ? sm[t - off] : 0;
        __syncthreads();
        sm[t] += a;
        __syncthreads();
    }
    if (t < NBUK) gbase[t] = sm[t] - v;
}

// ---------------- pass 2: per-bucket CSR finalize + dinv + rowptr ----------------
__global__ __launch_bounds__(256) void csr2_kernel(const int* __restrict__ gcnt,
                                                   const int* __restrict__ gbase,
                                                   const int* __restrict__ bucket_data,
                                                   float* __restrict__ dinv,
                                                   int* __restrict__ rowptr,
                                                   int* __restrict__ csr_src) {
    __shared__ int counts[256];
    __shared__ int offs[256];
    __shared__ int counts2[256];
    const int t = threadIdx.x;
    const int b = blockIdx.x;
    const int cb = min(gcnt[b], SLOT);
    const int base = gbase[b];
    const int* bd = bucket_data + b * SLOT;
    counts[t] = 0; counts2[t] = 0;
    __syncthreads();
    for (int i = t; i < cb; i += 256) atomicAdd(&counts[bd[i] & 255], 1);
    __syncthreads();
    int c = counts[t];
    for (int off = 1; off < 256; off <<= 1) {
        int a = (t >= off) ? counts[t - off] : 0;
        __syncthreads();
        counts[t] += a;
        __syncthreads();
    }
    int excl = counts[t] - c;
    offs[t] = excl;
    int node = b * 256 + t;
    if (node < NN) {
        dinv[node] = rsqrtf((float)c + 1.0f);
        rowptr[node] = base + excl;
    }
    if (b == NBUK - 1 && t == 0) rowptr[NN] = NE;
    __syncthreads();
    for (int i = t; i < cb; i += 256) {
        int p = bd[i];
        int local = p & 255;
        int pos = atomicAdd(&counts2[local], 1);
        csr_src[base + offs[local] + pos] = p >> 8;   // p>=0, arith shift ok
    }
}

// ---------------- weights fp32 -> bf16 (all three in one launch) ----------------
__global__ __launch_bounds__(256) void w2bf_all_kernel(const float* __restrict__ W1,
                                                       const float* __restrict__ W2,
                                                       const float* __restrict__ W3,
                                                       unsigned short* __restrict__ Wb1,
                                                       unsigned short* __restrict__ Wb2,
                                                       unsigned short* __restrict__ Wb3) {
    int i = blockIdx.x * 256 + threadIdx.x;           // grid covers 26624
    if (i < 16384) Wb1[i] = f2bf(W1[i]);
    else if (i < 24576) Wb2[i - 16384] = f2bf(W2[i - 16384]);
    else if (i < 26624) Wb3[i - 24576] = f2bf(W3[i - 24576]);
}

// ---------------- MFMA GEMM: hs[n,:] = ((relu?)A[n,:] @ W) * dinv[n], bf16 out ----------------
// Layouts [m89-verified]: A: m=lane&15, k=quad*8+j ; B: n=lane&15, k=quad*8+j ;
//                         C/D: col=lane&15, row=quad*4+reg.
template<int FIN, int FOUT, bool RELU_IN, bool A_BF16>
__global__ __launch_bounds__(256) void mfma_gemm(const void* __restrict__ in_,
                                                 const unsigned short* __restrict__ Wb,
                                                 const float* __restrict__ dinv,
                                                 unsigned short* __restrict__ out,
                                                 int N, int nwaves) {
    constexpr int NT = FOUT / 16;
    constexpr int KS = FIN / 32;
    const int lane = threadIdx.x & 63;
    const int wid  = (blockIdx.x * 256 + threadIdx.x) >> 6;
    const int ntile = wid % NT;
    const int col  = (lane & 15) + ntile * 16;
    const int quad = lane >> 4;
    const int koff = quad * 8;

    short8 bfrag[KS];
#pragma unroll
    for (int ks = 0; ks < KS; ++ks)
#pragma unroll
        for (int j = 0; j < 8; ++j)
            bfrag[ks][j] = (short)Wb[(ks * 32 + koff + j) * FOUT + col];

    const int MT = N / 16;                 // N == 100000 -> exact
    const int mstride = nwaves / NT;
    for (int mt = wid / NT; mt < MT; mt += mstride) {
        const int row = mt * 16 + (lane & 15);
        short8 afrag[KS];
        if (A_BF16) {
            const unsigned short* A = (const unsigned short*)in_ + (size_t)row * FIN + koff;
#pragma unroll
            for (int ks = 0; ks < KS; ++ks) {
                short8 a = *(const short8*)(A + ks * 32);
                if (RELU_IN) {
#pragma unroll
                    for (int j = 0; j < 8; ++j)
                        a[j] = (short)(((unsigned short)a[j] & 0x8000u) ? 0 : (unsigned short)a[j]);
                }
                afrag[ks] = a;
            }
        } else {
            const float* A = (const float*)in_ + (size_t)row * FIN + koff;
#pragma unroll
            for (int ks = 0; ks < KS; ++ks) {
                f32x4 v0 = *(const f32x4*)(A + ks * 32);
                f32x4 v1 = *(const f32x4*)(A + ks * 32 + 4);
#pragma unroll
                for (int j = 0; j < 4; ++j) {
                    float a0 = v0[j], a1 = v1[j];
                    if (RELU_IN) { a0 = fmaxf(a0, 0.f); a1 = fmaxf(a1, 0.f); }
                    afrag[ks][j]     = (short)f2bf(a0);
                    afrag[ks][j + 4] = (short)f2bf(a1);
                }
            }
        }
        f32x4 acc = {0.f, 0.f, 0.f, 0.f};
#pragma unroll
        for (int ks = 0; ks < KS; ++ks)
            acc = __builtin_amdgcn_mfma_f32_16x16x32_bf16(
                __builtin_bit_cast(bf16x8, afrag[ks]),
                __builtin_bit_cast(bf16x8, bfrag[ks]), acc, 0, 0, 0);
#pragma unroll
        for (int r = 0; r < 4; ++r) {
            int orow = mt * 16 + quad * 4 + r;
            out[(size_t)orow * FOUT + col] = f2bf(acc[r] * dinv[orow]);
        }
    }
}

// ---------------- gather-aggregate: agg[n] = dinv[n]*(hs[n] + sum_e hs[src]) + b ----------------
// Inner CSR loop unrolled x4: 4 independent row-gathers in flight per node-chain (MLP).
template<int F, bool OUT_BF16>
__global__ __launch_bounds__(256) void agg_kernel(const int* __restrict__ rowptr,
                                                  const int* __restrict__ csr_src,
                                                  const unsigned short* __restrict__ hs,
                                                  const float* __restrict__ dinv,
                                                  const float* __restrict__ b,
                                                  void* __restrict__ aggout, int N) {
    constexpr int TPN = F / 8;           // lanes per node (8 bf16 = 16B each)
    constexpr int NPB = 256 / TPN;
    int n = blockIdx.x * NPB + threadIdx.x / TPN;
    int c8 = (threadIdx.x % TPN) * 8;
    if (n >= N) return;
    int row = rowptr[n], end = rowptr[n + 1];
    float acc[8];
    {
        short8 h = *(const short8*)(hs + (size_t)n * F + c8);   // self term
#pragma unroll
        for (int j = 0; j < 8; ++j) acc[j] = bf2f((unsigned short)h[j]);
    }
    int j = row;
    for (; j + 4 <= end; j += 4) {
        int s0 = csr_src[j], s1 = csr_src[j + 1], s2 = csr_src[j + 2], s3 = csr_src[j + 3];
        short8 h0 = *(const short8*)(hs + (size_t)s0 * F + c8);
        short8 h1 = *(const short8*)(hs + (size_t)s1 * F + c8);
        short8 h2 = *(const short8*)(hs + (size_t)s2 * F + c8);
        short8 h3 = *(const short8*)(hs + (size_t)s3 * F + c8);
#pragma unroll
        for (int k = 0; k < 8; ++k)
            acc[k] += (bf2f((unsigned short)h0[k]) + bf2f((unsigned short)h1[k])) +
                      (bf2f((unsigned short)h2[k]) + bf2f((unsigned short)h3[k]));
    }
    for (; j < end; ++j) {
        int s = csr_src[j];
        short8 h = *(const short8*)(hs + (size_t)s * F + c8);
#pragma unroll
        for (int k = 0; k < 8; ++k) acc[k] += bf2f((unsigned short)h[k]);
    }
    float c = dinv[n];
    if (OUT_BF16) {
        short8 o;
#pragma unroll
        for (int k = 0; k < 8; ++k) o[k] = (short)f2bf(fmaf(acc[k], c, b[c8 + k]));
        *(short8*)((unsigned short*)aggout + (size_t)n * F + c8) = o;
    } else {
        f32x4 o0, o1;
#pragma unroll
        for (int k = 0; k < 4; ++k) {
            o0[k] = fmaf(acc[k], c, b[c8 + k]);
            o1[k] = fmaf(acc[k + 4], c, b[c8 + k + 4]);
        }
        float* of = (float*)aggout + (size_t)n * F + c8;
        *(f32x4*)of = o0;
        *(f32x4*)(of + 4) = o1;
    }
}

// ---------------- per-graph node ranges (batch is sorted) ----------------
__global__ __launch_bounds__(256) void grange_kernel(const int* __restrict__ batch,
                                                     int* __restrict__ gstart) {
    int g = blockIdx.x * 256 + threadIdx.x;
    if (g > NG) return;
    if (g == NG) { gstart[g] = NN; return; }
    int lo = 0, hi = NN;
    while (lo < hi) { int mid = (lo + hi) >> 1; if (batch[mid] < g) lo = mid + 1; else hi = mid; }
    gstart[g] = lo;
}

// ---------------- pool: pooled[g,:] = mean of h rows in [gstart[g], gstart[g+1]) ----------------
__global__ __launch_bounds__(256) void pool2_kernel(const float* __restrict__ h,
                                                    const int* __restrict__ gstart,
                                                    float* __restrict__ pooled) {
    __shared__ float sm[256];
    int g = blockIdx.x;
    int s = gstart[g], e = gstart[g + 1];
    int f = threadIdx.x & 31, slot = threadIdx.x >> 5;
    float acc = 0.f;
    for (int n = s + slot; n < e; n += 8) acc += h[(size_t)n * 32 + f];
    sm[threadIdx.x] = acc;
    __syncthreads();
    if (threadIdx.x < 128) sm[threadIdx.x] += sm[threadIdx.x + 128];
    __syncthreads();
    if (threadIdx.x < 64) sm[threadIdx.x] += sm[threadIdx.x + 64];
    __syncthreads();
    if (threadIdx.x < 32) {
        float v = sm[threadIdx.x] + sm[threadIdx.x + 32];
        float cntf = fmaxf((float)(e - s), 1.0f);
        pooled[(size_t)g * 32 + f] = v / cntf;
    }
}

// ---------------- epilogue ----------------
__global__ __launch_bounds__(256) void final_kernel(const float* __restrict__ pooled,
                                                    const float* __restrict__ Wl,
                                                    const float* __restrict__ bl,
                                                    const int* __restrict__ targets,
                                                    float* __restrict__ out) {
    __shared__ float red[256];
    float lsum = 0.0f;
    for (int g = threadIdx.x; g < NG; g += 256) {
        float acc = bl[0];
#pragma unroll
        for (int k = 0; k < 32; ++k)
            acc = fmaf(pooled[(size_t)g * 32 + k], Wl[k], acc);
        out[g] = 1.0f / (1.0f + expf(-acc));
        float y = (float)targets[g];
        lsum += fmaxf(acc, 0.0f) - acc * y + log1pf(expf(-fabsf(acc)));
    }
    red[threadIdx.x] = lsum;
    __syncthreads();
    for (int s = 128; s > 0; s >>= 1) {
        if (threadIdx.x < s) red[threadIdx.x] += red[threadIdx.x + s];
        __syncthreads();
    }
    if (threadIdx.x == 0) out[NG] = red[0] / (float)NG;
}

extern "C" void kernel_launch(void* const* d_in, const int* in_sizes, int n_in,
                              void* d_out, int out_size, void* d_ws, size_t ws_size,
                              hipStream_t stream) {
    const float* x       = (const float*)d_in[0];
    const int*   ei      = (const int*)d_in[1];
    const int*   batch   = (const int*)d_in[2];
    const int*   targets = (const int*)d_in[3];
    const float* W1 = (const float*)d_in[4];
    const float* b1 = (const float*)d_in[5];
    const float* W2 = (const float*)d_in[6];
    const float* b2 = (const float*)d_in[7];
    const float* W3 = (const float*)d_in[8];
    const float* b3 = (const float*)d_in[9];
    const float* Wl = (const float*)d_in[10];
    const float* bl = (const float*)d_in[11];
    float* out = (float*)d_out;
    char*  ws  = (char*)d_ws;

    const int* src = ei;
    const int* dst = ei + NE;

    // workspace layout (byte offsets, 512B aligned) — total ~68.3 MB
    float*          dinv    = (float*)(ws);                    //    400,384 B
    int*            rowptr  = (int*)(ws + 400384);             //    400,384 B (NN+1)
    int*            csr_src = (int*)(ws + 800768);             //  6,400,512 B
    unsigned short* Wb1     = (unsigned short*)(ws + 7201280); //     32,768 B
    unsigned short* Wb2     = (unsigned short*)(ws + 7234048); //     16,384 B
    unsigned short* Wb3     = (unsigned short*)(ws + 7250432); //      4,096 B
    int*            gstart  = (int*)(ws + 7254528);            //      8,704 B (NG+1)
    unsigned short* hsbuf   = (unsigned short*)(ws + 7263232); // 25,600,512 B
    unsigned short* aggbuf  = (unsigned short*)(ws + 32863744);// 25,600,512 B
    float*          pooled  = (float*)(ws + 58464256);         //    262,144 B
    int*            bdata   = (int*)(ws + 58726400);           //  9,609,216 B (391*6144*4)
    int*            gcnt    = (int*)(ws + 68335616);           //      2,048 B
    int*            gbase   = (int*)(ws + 68337664);           //      2,048 B

    // ---- CSR build (bucketed, no global scatter-atomics) ----
    hipMemsetAsync(gcnt, 0, 2048, stream);
    bin_kernel<<<(NE + CHUNK - 1) / CHUNK, 256, 0, stream>>>(src, dst, gcnt, bdata, NE);
    bbase_kernel<<<1, 512, 0, stream>>>(gcnt, gbase);
    csr2_kernel<<<NBUK, 256, 0, stream>>>(gcnt, gbase, bdata, dinv, rowptr, csr_src);

    // ---- independent small setup ----
    grange_kernel<<<9, 256, 0, stream>>>(batch, gstart);
    w2bf_all_kernel<<<104, 256, 0, stream>>>(W1, W2, W3, Wb1, Wb2, Wb3);

    const int GB = 1024;               // 4096 waves; NT in {8,4,2} all divide
    const int NWAVES = GB * 4;

    // ---- layer 1 ----
    mfma_gemm<128, 128, false, false><<<GB, 256, 0, stream>>>(x, Wb1, dinv, hsbuf, NN, NWAVES);
    agg_kernel<128, true><<<(NN + 15) / 16, 256, 0, stream>>>(rowptr, csr_src, hsbuf, dinv, b1, aggbuf, NN);

    // ---- layer 2 ----
    mfma_gemm<128, 64, true, true><<<GB, 256, 0, stream>>>(aggbuf, Wb2, dinv, hsbuf, NN, NWAVES);
    agg_kernel<64, true><<<(NN + 31) / 32, 256, 0, stream>>>(rowptr, csr_src, hsbuf, dinv, b2, aggbuf, NN);

    // ---- layer 3 (agg out fp32 for pooling) ----
    mfma_gemm<64, 32, true, true><<<GB, 256, 0, stream>>>(aggbuf, Wb3, dinv, hsbuf, NN, NWAVES);
    agg_kernel<32, false><<<(NN + 63) / 64, 256, 0, stream>>>(rowptr, csr_src, hsbuf, dinv, b3, aggbuf, NN);

    // ---- pool + epilogue ----
    pool2_kernel<<<NG, 256, 0, stream>>>((const float*)aggbuf, gstart, pooled);
    final_kernel<<<1, 256, 0, stream>>>(pooled, Wl, bl, targets, out);
}